// Round 4
// baseline (1377.872 us; speedup 1.0000x reference)
//
#include <hip/hip_runtime.h>
#include <math.h>

// ---------------------------------------------------------------------------
// Swin-v2 window attention, round 3: split-precision bf16 MFMA GEMMs.
//   x (fp32) --convx--> xh/xl bf16 planes
//   qkv GEMM: MFMA 16x16x32_bf16, 3-term split (hh + hl + lh)   -> qkvb fp32
//   attention (fp32 VALU, unchanged math) -> ah/al bf16 planes
//   proj GEMM: same MFMA kernel                                  -> out fp32
// W matrices pre-packed once per call into per-lane MFMA B-fragment order.
// Fragment layouts per cdna4 guide (m89-verified):
//   A: lane l holds A[l&15][(l>>4)*8 + j], j=0..7 (ushort8)
//   B: lane l holds B[(l>>4)*8 + j][l&15]
//   D: lane l, reg r -> row (l>>4)*4+r, col l&15
// ---------------------------------------------------------------------------

typedef unsigned short u16;
typedef unsigned int   u32;
using f32x4  = __attribute__((ext_vector_type(4))) float;
using s16x8  = __attribute__((ext_vector_type(8))) short;
using u16x4  = __attribute__((ext_vector_type(4))) unsigned short;

constexpr int C_ = 192;
constexpr int D_ = 576;
constexpr int HEADS_ = 6;
constexpr int TOK_TOTAL = 4 * 256 * 256;   // 262144

__device__ __forceinline__ u16 f2bf(float f) {          // round-to-nearest-even
    u32 u = __builtin_bit_cast(u32, f);
    return (u16)((u + 0x7FFFu + ((u >> 16) & 1u)) >> 16);
}
__device__ __forceinline__ float bf2f(u16 h) {
    u32 u = ((u32)h) << 16; return __builtin_bit_cast(float, u);
}

// ---------------- CPB: tab[225][2] -> relu(512) -> sigmoid(6)*16 ------------
__global__ void cpb_kernel(const float* __restrict__ w1, const float* __restrict__ b1,
                           const float* __restrict__ w2, float* __restrict__ tabo)
{
    int i = threadIdx.x;
    if (i >= 225) return;
    int a = i / 15, b = i % 15;
    float va = (float)(a - 7) * (8.0f / 7.0f);
    float vb = (float)(b - 7) * (8.0f / 7.0f);
    const float inv_log8 = 0.4808983469629878f;   // 1/ln(8)
    va = copysignf(log1pf(fabsf(va)) * inv_log8, va);
    vb = copysignf(log1pf(fabsf(vb)) * inv_log8, vb);
    float acc[HEADS_] = {0.f, 0.f, 0.f, 0.f, 0.f, 0.f};
    for (int j = 0; j < 512; ++j) {
        float h = fmaf(va, w1[j], fmaf(vb, w1[512 + j], b1[j]));
        h = fmaxf(h, 0.0f);
#pragma unroll
        for (int hh = 0; hh < HEADS_; ++hh)
            acc[hh] = fmaf(h, w2[j * HEADS_ + hh], acc[hh]);
    }
#pragma unroll
    for (int hh = 0; hh < HEADS_; ++hh)
        tabo[i * HEADS_ + hh] = 16.0f / (1.0f + expf(-acc[hh]));
}

// ---------------- W -> per-lane MFMA B-fragment pack (hi8 | lo8) ------------
// frag[((nb*6 + ks)*64 + lane)*16 + {0..7: hi, 8..15: lo}]
//   covers B[k = ks*32 + (lane>>4)*8 + j][col = nb*16 + (lane&15)]
__global__ void convw_kernel(const float* __restrict__ W, int N, u16* __restrict__ frag)
{
    int g = blockIdx.x * 256 + threadIdx.x;
    int total = (N >> 4) * 6 * 64;
    if (g >= total) return;
    int lane = g & 63, t = g >> 6;
    int ks = t % 6, nb = t / 6;
    int kb = ks * 32 + ((lane >> 4) << 3);
    int col = (nb << 4) + (lane & 15);
    u16* dst = frag + (size_t)g * 16;
#pragma unroll
    for (int j = 0; j < 8; ++j) {
        float w = W[(size_t)(kb + j) * N + col];
        u16 h = f2bf(w);
        dst[j] = h;
        dst[8 + j] = f2bf(w - bf2f(h));
    }
}

// ---------------- fp32 -> bf16 hi/lo planes ---------------------------------
__global__ __launch_bounds__(256)
void convx_kernel(const float* __restrict__ src, u16* __restrict__ hi,
                  u16* __restrict__ lo, int n4)
{
    int i = blockIdx.x * 256 + threadIdx.x;
    if (i >= n4) return;
    float4 v = ((const float4*)src)[i];
    float a[4] = {v.x, v.y, v.z, v.w};
    u16x4 h, l;
#pragma unroll
    for (int j = 0; j < 4; ++j) {
        u16 hh = f2bf(a[j]);
        h[j] = hh;
        l[j] = f2bf(a[j] - bf2f(hh));
    }
    ((u16x4*)hi)[i] = h;
    ((u16x4*)lo)[i] = l;
}

// ---------------- split-bf16 MFMA GEMM --------------------------------------
// C[m][n] = A[m][0:192] @ W[0:192][n] + bias,  A given as hi/lo bf16 planes
// block: 256 thr = 4 waves (2M x 2N); wave tile 32M x 96N; K-steps 6 x 32.
// MODE 0: qkv concat-bias over raw n; MODE 1: plain bias b0[n].
template <int NT, int MODE>
__global__ __launch_bounds__(256)
void mgemm(const u16* __restrict__ Ahi, const u16* __restrict__ Alo,
           const u16* __restrict__ frag, const float* __restrict__ b0,
           const float* __restrict__ b1, float* __restrict__ Cout)
{
    const int tid  = threadIdx.x;
    const int lane = tid & 63;
    const int wid  = tid >> 6;
    const int wm   = wid >> 1;          // 0..1 (M)
    const int wn   = wid & 1;           // 0..1 (N)
    const int m0   = blockIdx.x * 64 + wm * 32;
    const int n0   = blockIdx.y * 192 + wn * 96;
    const int l15  = lane & 15;
    const int lk   = (lane >> 4) << 3;  // 0,8,16,24
    const int nb0  = n0 >> 4;

    f32x4 acc[2][6];
#pragma unroll
    for (int i = 0; i < 2; ++i)
#pragma unroll
        for (int j = 0; j < 6; ++j) acc[i][j] = (f32x4){0.f, 0.f, 0.f, 0.f};

#pragma unroll 2
    for (int ks = 0; ks < 6; ++ks) {
        const int k = ks * 32 + lk;
        s16x8 a_h[2], a_l[2];
#pragma unroll
        for (int rb = 0; rb < 2; ++rb) {
            size_t off = (size_t)(m0 + rb * 16 + l15) * C_ + k;
            a_h[rb] = *(const s16x8*)(Ahi + off);
            a_l[rb] = *(const s16x8*)(Alo + off);
        }
#pragma unroll
        for (int cb = 0; cb < 6; ++cb) {
            const u16* bp = frag + (size_t)(((nb0 + cb) * 6 + ks) * 64 + lane) * 16;
            s16x8 b_h = *(const s16x8*)bp;
            s16x8 b_l = *(const s16x8*)(bp + 8);
#pragma unroll
            for (int rb = 0; rb < 2; ++rb) {
                acc[rb][cb] = __builtin_amdgcn_mfma_f32_16x16x32_bf16(a_h[rb], b_h, acc[rb][cb], 0, 0, 0);
                acc[rb][cb] = __builtin_amdgcn_mfma_f32_16x16x32_bf16(a_h[rb], b_l, acc[rb][cb], 0, 0, 0);
                acc[rb][cb] = __builtin_amdgcn_mfma_f32_16x16x32_bf16(a_l[rb], b_h, acc[rb][cb], 0, 0, 0);
            }
        }
    }

    const int rbase = (lane >> 4) << 2;   // D row block within 16x16
#pragma unroll
    for (int rb = 0; rb < 2; ++rb) {
        const int m = m0 + rb * 16 + rbase;
#pragma unroll
        for (int cb = 0; cb < 6; ++cb) {
            const int n = n0 + cb * 16 + l15;
            float bias;
            if (MODE == 0) bias = (n < 192) ? b0[n] : ((n < 384) ? 0.0f : b1[n - 384]);
            else           bias = b0[n];
#pragma unroll
            for (int r = 0; r < 4; ++r)
                Cout[(size_t)(m + r) * NT + n] = acc[rb][cb][r] + bias;
        }
    }
}

// ---------------- window attention: one wave per (window, head) -------------
// qkv chunk layout: [ct][576], per head offset h*96 : q[0:32) k[32:64) v[64:96)
// outputs bf16 hi/lo planes [ct][192] (feeds proj MFMA GEMM directly)
__global__ __launch_bounds__(64)
void attn_kernel(const float* __restrict__ qkv, const float* __restrict__ tabo,
                 const float* __restrict__ scale, u16* __restrict__ outh,
                 u16* __restrict__ outl)
{
    __shared__ __align__(16) float ks[64][36];
    __shared__ __align__(16) float vs[64][36];
    __shared__ float tab_s[225 * HEADS_];
    const int head = blockIdx.y;
    const int wr = blockIdx.x >> 5;
    const int wc = blockIdx.x & 31;
    const int t = threadIdx.x;
    const int r = t >> 3, cc = t & 7;
    const int lm = (wr * 8 + r) * 256 + wc * 8 + cc;
    const float* base = qkv + (size_t)lm * D_ + head * 96;

    for (int i = t; i < 225 * HEADS_; i += 64) tab_s[i] = tabo[i];

    float qr[32];
    {
        float ss = 0.f;
#pragma unroll
        for (int j = 0; j < 8; ++j) {
            float4 v4 = *(const float4*)(base + 4 * j);
            qr[4 * j] = v4.x; qr[4 * j + 1] = v4.y; qr[4 * j + 2] = v4.z; qr[4 * j + 3] = v4.w;
            ss += v4.x * v4.x + v4.y * v4.y + v4.z * v4.z + v4.w * v4.w;
        }
        float ls = expf(fminf(scale[head], 4.605170185988091f));   // min(s, ln 100)
        float sc = rsqrtf(fmaxf(ss, 1.55e-05f)) * ls;
#pragma unroll
        for (int j = 0; j < 32; ++j) qr[j] *= sc;
    }
    {
        float kr[32]; float ss = 0.f;
#pragma unroll
        for (int j = 0; j < 8; ++j) {
            float4 v4 = *(const float4*)(base + 32 + 4 * j);
            kr[4 * j] = v4.x; kr[4 * j + 1] = v4.y; kr[4 * j + 2] = v4.z; kr[4 * j + 3] = v4.w;
            ss += v4.x * v4.x + v4.y * v4.y + v4.z * v4.z + v4.w * v4.w;
        }
        float sck = rsqrtf(fmaxf(ss, 1.55e-05f));
#pragma unroll
        for (int j = 0; j < 32; ++j) ks[t][j] = kr[j] * sck;
#pragma unroll
        for (int j = 0; j < 8; ++j) {
            float4 v4 = *(const float4*)(base + 64 + 4 * j);
            vs[t][4 * j] = v4.x; vs[t][4 * j + 1] = v4.y;
            vs[t][4 * j + 2] = v4.z; vs[t][4 * j + 3] = v4.w;
        }
    }
    __syncthreads();

    float s[64];
    float mx = -3.0e38f;
    const int ri = r + 7, ci = cc + 7;
#pragma unroll
    for (int kk = 0; kk < 64; ++kk) {
        const float* kp = &ks[kk][0];
        float d = 0.f;
#pragma unroll
        for (int j = 0; j < 32; ++j) d = fmaf(qr[j], kp[j], d);
        const int r2 = kk >> 3, c2 = kk & 7;
        d += tab_s[((ri - r2) * 15 + (ci - c2)) * HEADS_ + head];
        s[kk] = d;
        mx = fmaxf(mx, d);
    }
    float sum = 0.f;
#pragma unroll
    for (int kk = 0; kk < 64; ++kk) { float p = expf(s[kk] - mx); s[kk] = p; sum += p; }
    const float inv = 1.0f / sum;
    float acc[32] = {};
#pragma unroll
    for (int kk = 0; kk < 64; ++kk) {
        const float p = s[kk];
        const float* vp = &vs[kk][0];
#pragma unroll
        for (int j = 0; j < 32; ++j) acc[j] = fmaf(p, vp[j], acc[j]);
    }
    const size_t ob = (size_t)lm * C_ + head * 32;
#pragma unroll
    for (int g = 0; g < 4; ++g) {
        s16x8 ph, pl;
#pragma unroll
        for (int e = 0; e < 8; ++e) {
            float o = acc[8 * g + e] * inv;
            u16 h = f2bf(o);
            ph[e] = (short)h;
            pl[e] = (short)f2bf(o - bf2f(h));
        }
        *(s16x8*)(outh + ob + 8 * g) = ph;
        *(s16x8*)(outl + ob + 8 * g) = pl;
    }
}

// ---------------------------------------------------------------------------
extern "C" void kernel_launch(void* const* d_in, const int* in_sizes, int n_in,
                              void* d_out, int out_size, void* d_ws, size_t ws_size,
                              hipStream_t stream)
{
    const float* x     = (const float*)d_in[0];
    const float* qkv_w = (const float*)d_in[1];
    const float* q_b   = (const float*)d_in[2];
    const float* v_b   = (const float*)d_in[3];
    const float* scale = (const float*)d_in[4];
    const float* w1    = (const float*)d_in[5];
    const float* b1    = (const float*)d_in[6];
    const float* w2    = (const float*)d_in[7];
    const float* pw    = (const float*)d_in[8];
    const float* pb    = (const float*)d_in[9];
    float* out = (float*)d_out;

    // fixed ws: tabo 8KB | wq frag 442368 B | wp frag 147456 B (all 256-mult)
    const size_t FIXED = 8192 + 442368 + 147456;   // 598016
    int nchunk = 8;
    while (nchunk < 64) {
        size_t ctc = (size_t)TOK_TOTAL / nchunk;
        if (FIXED + ctc * 3840 <= ws_size) break;
        nchunk *= 2;
    }
    const size_t ct = (size_t)TOK_TOTAL / nchunk;

    char* bptr = (char*)d_ws;
    float* tabo = (float*)bptr;
    u16* wq = (u16*)(bptr + 8192);
    u16* wp = (u16*)(bptr + 8192 + 442368);
    char* p = bptr + FIXED;
    u16* xh = (u16*)p;        p += ct * 384;
    u16* xl = (u16*)p;        p += ct * 384;
    float* qkvb = (float*)p;  p += ct * 2304;
    u16* ah = (u16*)p;        p += ct * 384;
    u16* al = (u16*)p;

    cpb_kernel<<<dim3(1), dim3(256), 0, stream>>>(w1, b1, w2, tabo);
    convw_kernel<<<dim3(54), dim3(256), 0, stream>>>(qkv_w, D_, wq);   // 36*6*64=13824
    convw_kernel<<<dim3(18), dim3(256), 0, stream>>>(pw, C_, wp);      // 12*6*64=4608

    const int mblocks = (int)(ct / 64);
    const int wrows   = (int)(ct / 2048);
    for (int c = 0; c < nchunk; ++c) {
        const float* xc = x + (size_t)c * ct * C_;
        float* oc = out + (size_t)c * ct * C_;
        convx_kernel<<<dim3((int)(ct * 48 / 256)), dim3(256), 0, stream>>>(xc, xh, xl, (int)(ct * 48));
        mgemm<576, 0><<<dim3(mblocks, 3), dim3(256), 0, stream>>>(xh, xl, wq, q_b, v_b, qkvb);
        attn_kernel<<<dim3(wrows * 32, 6), dim3(64), 0, stream>>>(qkvb, tabo, scale, ah, al);
        mgemm<192, 1><<<dim3(mblocks, 1), dim3(256), 0, stream>>>(ah, al, wp, pb, nullptr, oc);
    }
}